// Round 15
// baseline (712.690 us; speedup 1.0000x reference)
//
#include <hip/hip_runtime.h>
#include <math.h>

#define N_NODES 4096
#define DIM 384
#define QKVD 1152
#define N_EDGES 131072
#define N_HEADS 8
#define DH 48
#define N_LAYERS 3

typedef short v4s __attribute__((ext_vector_type(4)));
typedef short v8s __attribute__((ext_vector_type(8)));
typedef float v4f __attribute__((ext_vector_type(4)));

#define MFMA32(A, B, C) __builtin_amdgcn_mfma_f32_16x16x32_bf16(A, B, C, 0, 0, 0)
#define MFMA16(A, B, C) __builtin_amdgcn_mfma_f32_16x16x16bf16_1k(A, B, C, 0, 0, 0)
#define EXP2F(x) __builtin_exp2f(x)

// ======================= CSR build (counting sort by dst) =======================

__global__ void zero_counts_kernel(int* counts, int* cursor) {
  int i = blockIdx.x * blockDim.x + threadIdx.x;
  if (i < N_NODES) { counts[i] = 0; cursor[i] = 0; }
}

__global__ void count_kernel(const int* __restrict__ dst, int* counts) {
  int e = blockIdx.x * blockDim.x + threadIdx.x;
  if (e < N_EDGES) atomicAdd(&counts[dst[e]], 1);
}

__global__ __launch_bounds__(1024) void scan_kernel(const int* __restrict__ counts,
                                                    int* __restrict__ offsets) {
  __shared__ int s[1024];
  int t = threadIdx.x;
  int base = t * 4;
  int c[4];
  int sum = 0;
  #pragma unroll
  for (int i = 0; i < 4; i++) { c[i] = counts[base + i]; sum += c[i]; }
  s[t] = sum;
  __syncthreads();
  for (int off = 1; off < 1024; off <<= 1) {
    int v = (t >= off) ? s[t - off] : 0;
    __syncthreads();
    s[t] += v;
    __syncthreads();
  }
  int excl = s[t] - sum;
  #pragma unroll
  for (int i = 0; i < 4; i++) { offsets[base + i] = excl; excl += c[i]; }
  if (t == 1023) offsets[N_NODES] = s[1023];
}

__global__ void scatter_kernel(const int* __restrict__ dst, const int* __restrict__ src,
                               const int* __restrict__ offsets, int* cursor,
                               int* __restrict__ ssrc) {
  int e = blockIdx.x * blockDim.x + threadIdx.x;
  if (e < N_EDGES) {
    int d = dst[e];
    int pos = atomicAdd(&cursor[d], 1);
    ssrc[offsets[d] + pos] = src[e];
  }
}

// ======================= bf16 split helpers =======================

__device__ __forceinline__ void bsplit(float v, ushort& hi, ushort& lo) {
  unsigned b = __float_as_uint(v);
  unsigned hb = b & 0xFFFF0000u;
  hi = (ushort)(b >> 16);
  float r = v - __uint_as_float(hb);
  lo = (ushort)(__float_as_uint(r) >> 16);
}

// pack hi16 of (a,b) into one dword (a in low half) — bf16 truncation
__device__ __forceinline__ unsigned pack2hi(float a, float b) {
  return __builtin_amdgcn_perm(__float_as_uint(b), __float_as_uint(a), 0x07060302u);
}

// ======================= neighbor aggregation (+ split epilogue) =================
// R22: vectorized float4 gather + ushort4 stores (measured neutral, kept).

__global__ __launch_bounds__(128) void aggregate_kernel(const float* __restrict__ h,
    const int* __restrict__ ssrc, const int* __restrict__ offsets,
    ushort* __restrict__ aggH, ushort* __restrict__ aggL) {
  int i = blockIdx.x;
  int t = threadIdx.x;
  if (t >= 96) return;                 // 96 x float4 = 384 channels
  int e0 = offsets[i], e1 = offsets[i + 1];
  float a0 = 0.f, a1 = 0.f, a2 = 0.f, a3 = 0.f;
  int e = e0;
  for (; e + 2 <= e1; e += 2) {        // 2x unroll: 2 independent b128 loads
    const float4 x = *((const float4*)(h + (size_t)ssrc[e] * DIM) + t);
    const float4 y = *((const float4*)(h + (size_t)ssrc[e + 1] * DIM) + t);
    a0 += x.x; a1 += x.y; a2 += x.z; a3 += x.w;
    a0 += y.x; a1 += y.y; a2 += y.z; a3 += y.w;
  }
  if (e < e1) {
    const float4 x = *((const float4*)(h + (size_t)ssrc[e] * DIM) + t);
    a0 += x.x; a1 += x.y; a2 += x.z; a3 += x.w;
  }
  ushort4 H, L;
  bsplit(a0, H.x, L.x); bsplit(a1, H.y, L.y);
  bsplit(a2, H.z, L.z); bsplit(a3, H.w, L.w);
  size_t base = (size_t)i * DIM + 4 * t;
  *(ushort4*)(aggH + base) = H;
  *(ushort4*)(aggL + base) = L;
}

// ======================= weight prep kernels =======================

__global__ void transpose_split_kernel(const float* __restrict__ Wc,
    ushort* __restrict__ wctH, ushort* __restrict__ wctL) {
  __shared__ float s[32][33];
  const int l = blockIdx.z;
  const float* W = Wc + (size_t)l * DIM * DIM;
  int tx = threadIdx.x, ty = threadIdx.y;
  s[ty][tx] = W[(size_t)(blockIdx.y * 32 + ty) * DIM + blockIdx.x * 32 + tx];
  __syncthreads();
  float v = s[tx][ty];
  ushort hi, lo;
  bsplit(v, hi, lo);
  size_t off = (size_t)l * DIM * DIM + (size_t)(blockIdx.x * 32 + ty) * DIM + blockIdx.y * 32 + tx;
  wctH[off] = hi;
  wctL[off] = lo;
}

__global__ void split_kernel(const float* __restrict__ src,
    ushort* __restrict__ hi, ushort* __restrict__ lo, int n) {
  int i = (blockIdx.x * 256 + threadIdx.x) * 4;
  if (i >= n) return;
  float4 v = *(const float4*)(src + i);
  ushort4 H, L;
  bsplit(v.x, H.x, L.x); bsplit(v.y, H.y, L.y);
  bsplit(v.z, H.z, L.z); bsplit(v.w, H.w, L.w);
  *(ushort4*)(hi + i) = H;
  *(ushort4*)(lo + i) = L;
}

// wibc[l][i] = dot(Wi[i,:], b_conv[l,:])
__global__ __launch_bounds__(256) void wibc_kernel(const float* __restrict__ Wi,
    const float* __restrict__ bconv, float* __restrict__ wibc) {
  int gw = (blockIdx.x * 256 + threadIdx.x) >> 6;
  int lane = threadIdx.x & 63;
  if (gw >= 3 * QKVD) return;
  int l = gw / QKVD, i = gw - l * QKVD;
  const float* w = Wi + (size_t)i * DIM;
  const float* b = bconv + (size_t)l * DIM;
  float s = 0.f;
  #pragma unroll
  for (int c = 0; c < 6; c++) s += w[lane + c * 64] * b[lane + c * 64];
  #pragma unroll
  for (int off = 32; off >= 1; off >>= 1) s += __shfl_xor(s, off, 64);
  if (lane == 0) wibc[gw] = s;
}

// ======================= split-bf16 MFMA GEMM cores ==============================

template<int K>
__device__ __forceinline__ void mfma_core(
    const ushort* __restrict__ Ah, const ushort* __restrict__ Al,
    const ushort* __restrict__ Bh, const ushort* __restrict__ Bl,
    int aRow0, int bRow0, int li, int quad, v4f acc[4][4])
{
  for (int k0 = 0; k0 < K; k0 += 32) {
    v8s Afh[4], Afl[4], Bfh[4], Bfl[4];
    #pragma unroll
    for (int t = 0; t < 4; t++) {
      size_t ao = (size_t)(aRow0 + t * 16 + li) * K + k0 + quad * 8;
      size_t bo = (size_t)(bRow0 + t * 16 + li) * K + k0 + quad * 8;
      Afh[t] = *(const v8s*)(Ah + ao);
      Afl[t] = *(const v8s*)(Al + ao);
      Bfh[t] = *(const v8s*)(Bh + bo);
      Bfl[t] = *(const v8s*)(Bl + bo);
    }
    #pragma unroll
    for (int mt = 0; mt < 4; mt++)
      #pragma unroll
      for (int nt = 0; nt < 4; nt++) {
        v4f a = acc[mt][nt];
        a = MFMA32(Afh[mt], Bfh[nt], a);
        a = MFMA32(Afl[mt], Bfh[nt], a);
        a = MFMA32(Afh[mt], Bfl[nt], a);
        acc[mt][nt] = a;
      }
  }
}

// 2x2-tile variant (32x32 per wave) — for small-output GEMMs needing more blocks
template<int K>
__device__ __forceinline__ void mfma_core2(
    const ushort* __restrict__ Ah, const ushort* __restrict__ Al,
    const ushort* __restrict__ Bh, const ushort* __restrict__ Bl,
    int aRow0, int bRow0, int li, int quad, v4f acc[2][2])
{
  for (int k0 = 0; k0 < K; k0 += 32) {
    v8s Afh[2], Afl[2], Bfh[2], Bfl[2];
    #pragma unroll
    for (int t = 0; t < 2; t++) {
      size_t ao = (size_t)(aRow0 + t * 16 + li) * K + k0 + quad * 8;
      size_t bo = (size_t)(bRow0 + t * 16 + li) * K + k0 + quad * 8;
      Afh[t] = *(const v8s*)(Ah + ao);
      Afl[t] = *(const v8s*)(Al + ao);
      Bfh[t] = *(const v8s*)(Bh + bo);
      Bfl[t] = *(const v8s*)(Bl + bo);
    }
    #pragma unroll
    for (int mt = 0; mt < 2; mt++)
      #pragma unroll
      for (int nt = 0; nt < 2; nt++) {
        v4f a = acc[mt][nt];
        a = MFMA32(Afh[mt], Bfh[nt], a);
        a = MFMA32(Afl[mt], Bfh[nt], a);
        a = MFMA32(Afh[mt], Bfl[nt], a);
        acc[mt][nt] = a;
      }
  }
}

// --- weight-prep GEMM: Wf[l] = Wi @ Wct[l] ---
__global__ __launch_bounds__(256) void wprep_gemm(
    const ushort* __restrict__ wiH, const ushort* __restrict__ wiL,
    const ushort* __restrict__ wctH, const ushort* __restrict__ wctL,
    ushort* __restrict__ wfH, ushort* __restrict__ wfL)
{
  const int l = blockIdx.z;
  const ushort* Bh = wctH + (size_t)l * DIM * DIM;
  const ushort* Bl = wctL + (size_t)l * DIM * DIM;
  ushort* oH = wfH + (size_t)l * QKVD * DIM;
  ushort* oL = wfL + (size_t)l * QKVD * DIM;
  const int tid = threadIdx.x;
  const int lane = tid & 63, li = lane & 15, quad = lane >> 4;
  const int w = tid >> 6, wm = w & 1, wn = w >> 1;
  const int aRow0 = blockIdx.x * 128 + wm * 64;
  const int bRow0 = blockIdx.y * 128 + wn * 64;
  v4f acc[4][4] = {};
  mfma_core<DIM>(wiH, wiL, Bh, Bl, aRow0, bRow0, li, quad, acc);
  #pragma unroll
  for (int mt = 0; mt < 4; mt++) {
    int i0 = aRow0 + mt * 16 + quad * 4;
    #pragma unroll
    for (int nt = 0; nt < 4; nt++) {
      int j = bRow0 + nt * 16 + li;
      #pragma unroll
      for (int r = 0; r < 4; r++) {
        ushort hi, lo;
        bsplit(acc[mt][nt][r], hi, lo);
        oH[(size_t)(i0 + r) * DIM + j] = hi;
        oL[(size_t)(i0 + r) * DIM + j] = lo;
      }
    }
  }
}

// --- fused qkv GEMM ---
// R23: retiled 128x128 -> 64x64 (grid (9,32)=288 -> (18,64)=1152 blocks).
// 288 blocks on 256 CUs was 1.125 blocks/CU = 1 WAVE/SIMD + a straggler
// round; with mfma_core's direct-global fragment loads (~192 x 16B dependent
// loads/thread, no LDS staging) there was zero TLP to hide L2 latency.
// 1152 blocks = 4.5/CU, 18 waves/CU; fragments L2/L1-hot (wf shared across
// 64 y-blocks, agg across 18 x-blocks). Part mapping stays clean: 6 x-blocks
// per Q/K/V part. Per-element MFMA chain order unchanged -> bit-identical.
// K/V tile-image layouts unchanged (R16); V writeout LDS panel now [64][68].
__global__ __launch_bounds__(256) void qkv_gemm(
    const ushort* __restrict__ wfH, const ushort* __restrict__ wfL,
    const ushort* __restrict__ aggH, const ushort* __restrict__ aggL,
    const float* __restrict__ wibc_l, const float* __restrict__ b_in,
    const int* __restrict__ deg,
    ushort* __restrict__ qhi, ushort* __restrict__ qlo,
    ushort* __restrict__ ktb, ushort* __restrict__ vtb)
{
  __shared__ ushort lhi[64][68];   // padded rows: ushort4-aligned, bank-shifted
  __shared__ ushort llo[64][68];
  const int tid = threadIdx.x;
  const int lane = tid & 63, li = lane & 15, quad = lane >> 4;
  const int w = tid >> 6, wm = w & 1, wn = w >> 1;
  const int bx = blockIdx.x;                      // 0..17 (6 per part)
  const int by = blockIdx.y;                      // 0..63
  const int aRow0 = bx * 64 + wm * 32;            // channel base
  const int bRow0 = by * 64 + wn * 32;            // node base
  v4f acc[2][2] = {};
  mfma_core2<DIM>(wfH, wfL, aggH, aggL, aRow0, bRow0, li, quad, acc);

  const float cq = 0.20823507f;  // log2(e)/sqrt(48)
  int node[2]; float degf[2];
  #pragma unroll
  for (int nt = 0; nt < 2; nt++) {
    node[nt] = bRow0 + nt * 16 + li;
    degf[nt] = (float)deg[node[nt]];
  }

  if (bx < 12) {
    // ---- Q (bx<6) and K (6<=bx<12) blocks: direct epilogue ----
    #pragma unroll
    for (int mt = 0; mt < 2; mt++) {
      const int c0 = aRow0 + mt * 16 + quad * 4;
      const int part = c0 / DIM;
      const int cm = c0 - part * DIM;
      const int hd = cm / DH;
      const int d0 = cm - hd * DH;
      float wb[4], bb[4];
      #pragma unroll
      for (int r = 0; r < 4; r++) { wb[r] = wibc_l[c0 + r]; bb[r] = b_in[c0 + r]; }
      #pragma unroll
      for (int nt = 0; nt < 2; nt++) {
        float v0 = acc[mt][nt][0] + degf[nt] * wb[0] + bb[0];
        float v1 = acc[mt][nt][1] + degf[nt] * wb[1] + bb[1];
        float v2 = acc[mt][nt][2] + degf[nt] * wb[2] + bb[2];
        float v3 = acc[mt][nt][3] + degf[nt] * wb[3] + bb[3];
        if (part == 0) {
          v0 *= cq; v1 *= cq; v2 *= cq; v3 *= cq;
          ushort4 H, L;
          bsplit(v0, H.x, L.x); bsplit(v1, H.y, L.y);
          bsplit(v2, H.z, L.z); bsplit(v3, H.w, L.w);
          size_t off = ((size_t)hd * N_NODES + node[nt]) * DH + d0;
          *(ushort4*)(qhi + off) = H;
          *(ushort4*)(qlo + off) = L;
        } else {
          ushort4 H, L;
          bsplit(v0, H.x, L.x); bsplit(v1, H.y, L.y);
          bsplit(v2, H.z, L.z); bsplit(v3, H.w, L.w);
          int kt = node[nt] >> 5, rc = node[nt] & 31;
          size_t base = (size_t)(hd * 128 + kt) * 4096 + (size_t)rc * 128;
          int ch = d0 >> 3, half = ((d0 >> 2) & 1) * 4;
          *(ushort4*)(ktb + base + ((ch ^ (rc & 7)) << 3) + half) = H;
          *(ushort4*)(ktb + base + (((ch + 6) ^ (rc & 7)) << 3) + half) = L;
        }
      }
    }
  } else {
    // ---- V blocks (bx 12..17, channels 768..1151): LDS-coalesced path ----
    #pragma unroll
    for (int mt = 0; mt < 2; mt++) {
      const int c0 = aRow0 + mt * 16 + quad * 4;      // global qkv channel
      const int lc0 = (wm * 32 + mt * 16 + quad * 4); // 0..63 within block
      float wb[4], bb[4];
      #pragma unroll
      for (int r = 0; r < 4; r++) { wb[r] = wibc_l[c0 + r]; bb[r] = b_in[c0 + r]; }
      #pragma unroll
      for (int nt = 0; nt < 2; nt++) {
        const int ln = wn * 32 + nt * 16 + li;        // 0..63 local node
        float vv[4];
        vv[0] = acc[mt][nt][0] + degf[nt] * wb[0] + bb[0];
        vv[1] = acc[mt][nt][1] + degf[nt] * wb[1] + bb[1];
        vv[2] = acc[mt][nt][2] + degf[nt] * wb[2] + bb[2];
        vv[3] = acc[mt][nt][3] + degf[nt] * wb[3] + bb[3];
        #pragma unroll
        for (int r = 0; r < 4; r++) {
          ushort hi, lo;
          bsplit(vv[r], hi, lo);
          lhi[lc0 + r][ln] = hi;
          llo[lc0 + r][ln] = lo;
        }
      }
    }
    __syncthreads();
    // cooperative writeout: 1024 slots = 64 lc x 2 ktl x 8 g; 4/thread.
    #pragma unroll
    for (int it = 0; it < 4; it++) {
      int item = it * 256 + tid;
      int lc = item >> 4;
      int rem = item & 15;
      int ktl = rem >> 3, g = rem & 7;
      int c = (bx - 12) * 64 + lc;         // v-channel 0..383
      int hd = c / DH, row = c - hd * DH;  // head, d-row 0..47
      int kt = by * 2 + ktl;               // tile 0..127
      ushort4 H = *(const ushort4*)&lhi[lc][ktl * 32 + g * 4];
      ushort4 L = *(const ushort4*)&llo[lc][ktl * 32 + g * 4];
      size_t base = (size_t)(hd * 128 + kt) * 3072 + (size_t)row * 64
                  + ((g ^ (row & 7)) << 3);
      *(ushort4*)(vtb + base) = H;
      *(ushort4*)(vtb + base + 4) = L;
    }
  }
}

// --- attn-out GEMM: h = relu(ao @ Wao^T + b_ao + h) ---
// R20: retiled 128x128 -> 64x64 (grid 96 -> 384 blocks); full-CU coverage.
__global__ __launch_bounds__(256) void outproj_gemm(
    const ushort* __restrict__ aoH, const ushort* __restrict__ aoL,
    const ushort* __restrict__ waoH, const ushort* __restrict__ waoL,
    const float* __restrict__ b_ao, float* __restrict__ h)
{
  const int tid = threadIdx.x;
  const int lane = tid & 63, li = lane & 15, quad = lane >> 4;
  const int w = tid >> 6, wm = w & 1, wn = w >> 1;
  const int aRow0 = blockIdx.x * 64 + wm * 32;   // node base
  const int bRow0 = blockIdx.y * 64 + wn * 32;   // channel base
  v4f acc[2][2] = {};
  mfma_core2<DIM>(aoH, aoL, waoH, waoL, aRow0, bRow0, li, quad, acc);
  #pragma unroll
  for (int mt = 0; mt < 2; mt++) {
    int m0 = aRow0 + mt * 16 + quad * 4;
    #pragma unroll
    for (int nt = 0; nt < 2; nt++) {
      int n = bRow0 + nt * 16 + li;
      float ba = b_ao[n];
      #pragma unroll
      for (int r = 0; r < 4; r++) {
        size_t off = (size_t)(m0 + r) * DIM + n;
        float v = acc[mt][nt][r] + ba + h[off];
        h[off] = fmaxf(v, 0.f);
      }
    }
  }
}

// ======================= MFMA flash attention (split-bf16, KV-split 4) ==========
// R16 configuration — the measured best (101-103 us/dispatch, reproduced
// across 5 runs). 32-kcol tiles, LDS double-buffer, 1 __syncthreads-pair per
// tile, 4 blocks/CU.

#define NT_TILES 32
#define K_TILE_B 8192
#define V_TILE_B 6144
#define TILE_B   (K_TILE_B + V_TILE_B)   // 14336; x2 buffers = 28672

__global__ __launch_bounds__(256, 4) void attn_kernel(
    const ushort* __restrict__ qhi, const ushort* __restrict__ qlo,
    const ushort* __restrict__ ktb, const ushort* __restrict__ vtb,
    float* __restrict__ Opart0, float* __restrict__ Opart1,
    float* __restrict__ Opart2, float* __restrict__ Opart3,
    float* __restrict__ mpart, float* __restrict__ lpart)
{
  const int head = blockIdx.y;
  const int qy = blockIdx.x;            // 0..31, 128 q-rows each
  const int z = blockIdx.z;             // 0..3 KV quarter (32 tiles of 32 kcols)
  const int tid = threadIdx.x;
  const int w = tid >> 6;
  const int lane = tid & 63;
  const int li = lane & 15, quad = lane >> 4;
  const int lx = li & 7;

  __shared__ __align__(16) char smem[2][TILE_B];

  // ---- resident Q fragments: wave w owns q-rows qy*128 + 32w + [0,32) ----
  const size_t headQ = (size_t)head * N_NODES * DH;
  const int qRow0 = qy * 128 + 32 * w;
  v8s q0h[2], q0l[2];
  v4s q1h[2], q1l[2];
  #pragma unroll
  for (int qt = 0; qt < 2; qt++) {
    const ushort* qr = qhi + headQ + (size_t)(qRow0 + 16 * qt + li) * DH;
    const ushort* ql = qlo + headQ + (size_t)(qRow0 + 16 * qt + li) * DH;
    q0h[qt] = *(const v8s*)(qr + quad * 8);
    q0l[qt] = *(const v8s*)(ql + quad * 8);
    q1h[qt] = *(const v4s*)(qr + 32 + quad * 4);
    q1l[qt] = *(const v4s*)(ql + 32 + quad * 4);
  }

  v4f ot[3][2];
  #pragma unroll
  for (int mt = 0; mt < 3; mt++)
    #pragma unroll
    for (int qt = 0; qt < 2; qt++)
      ot[mt][qt] = (v4f){0.f, 0.f, 0.f, 0.f};
  float m2[2] = {-3.0e38f, -3.0e38f};
  float lsum[2] = {0.f, 0.f};

  // ---- global tile-image bases for this (head, quarter) ----
  const char* gK = (const char*)ktb + (size_t)(head * 128 + z * 32) * K_TILE_B;
  const char* gV = (const char*)vtb + (size_t)(head * 128 + z * 32) * V_TILE_B;

  // ---- loop-invariant swizzled LDS read offsets ----
  const int koff_h  = ((quad ^ lx) << 4);
  const int koff_l  = (((6 + quad) ^ lx) << 4);
  const int koff_t0 = (((4 + (quad >> 1)) ^ lx) << 4) + ((quad & 1) << 3);
  const int koff_t1 = (((10 + (quad >> 1)) ^ lx) << 4) + ((quad & 1) << 3);

  // stage one tile (14 x 1KB chunks; wave w takes chunks w, w+4, w+8, w+12<14)
  auto stage = [&](char* sbase, int t) {
    const char* kt_ = gK + (size_t)t * K_TILE_B;
    const char* vt_ = gV + (size_t)t * V_TILE_B;
    #pragma unroll
    for (int j = 0; j < 4; j++) {
      const int ch = w + 4 * j;               // wave-uniform
      if (ch < 14) {
        const char* src = (ch < 8) ? (kt_ + (size_t)ch * 1024 + (size_t)lane * 16)
                                   : (vt_ + (size_t)(ch - 8) * 1024 + (size_t)lane * 16);
        __builtin_amdgcn_global_load_lds(
            (const __attribute__((address_space(1))) unsigned int*)src,
            (__attribute__((address_space(3))) unsigned int*)(sbase + ch * 1024),
            16, 0, 0);
      }
    }
  };

  auto compute = [&](const char* sbase) {
    const char* sK = sbase;
    const char* sV = sbase + K_TILE_B;
    #pragma unroll
    for (int ktl = 0; ktl < 2; ktl++) {
      // ---- K fragments (conflict-free swizzled reads) ----
      const char* kr = sK + ktl * 4096 + li * 256;
      v8s kh = *(const v8s*)(kr + koff_h);
      v8s kl = *(const v8s*)(kr + koff_l);
      v4s th = *(const v4s*)(kr + koff_t0);
      v4s tl = *(const v4s*)(kr + koff_t1);

      // ---- S^T = K·Q^T (split-3 exact, log2-domain) ----
      v4f s[2];
      #pragma unroll
      for (int qt = 0; qt < 2; qt++) {
        v4f a = (v4f){0.f, 0.f, 0.f, 0.f};
        a = MFMA32(kh, q0h[qt], a);
        a = MFMA32(kl, q0h[qt], a);
        a = MFMA32(kh, q0l[qt], a);
        a = MFMA16(th, q1h[qt], a);
        a = MFMA16(tl, q1h[qt], a);
        a = MFMA16(th, q1l[qt], a);
        s[qt] = a;
      }

      // ---- V fragments for this ktl (hi|lo interleaved in one b128) ----
      const int vcoff = (((4 * ktl + quad) ^ lx) << 4);
      v4s vh[3], vl[3];
      #pragma unroll
      for (int mt = 0; mt < 3; mt++) {
        v8s vv = *(const v8s*)(sV + mt * 2048 + li * 128 + vcoff);
        vh[mt] = __builtin_shufflevector(vv, vv, 0, 1, 2, 3);
        vl[mt] = __builtin_shufflevector(vv, vv, 4, 5, 6, 7);
      }

      // ---- guarded-base softmax + PV, fused per ktl (exact) ----
      #pragma unroll
      for (int qt = 0; qt < 2; qt++) {
        float mx = fmaxf(fmaxf(s[qt][0], s[qt][1]), fmaxf(s[qt][2], s[qt][3]));
        if (__any(mx > m2[qt] + 40.f)) {          // wave-uniform, rare
          float mr = fmaxf(mx, __shfl_xor(mx, 16, 64));
          mr = fmaxf(mr, __shfl_xor(mr, 32, 64)); // row-uniform new max
          float a = EXP2F(m2[qt] - fmaxf(m2[qt], mr));
          m2[qt] = fmaxf(m2[qt], mr);
          lsum[qt] *= a;
          #pragma unroll
          for (int mt = 0; mt < 3; mt++) ot[mt][qt] *= a;
        }
        float p0 = EXP2F(s[qt][0] - m2[qt]);      // bounded <= 2^40
        float p1 = EXP2F(s[qt][1] - m2[qt]);
        float p2 = EXP2F(s[qt][2] - m2[qt]);
        float p3 = EXP2F(s[qt][3] - m2[qt]);
        lsum[qt] += (p0 + p1) + (p2 + p3);
        union { uint2 u; v4s v; } uh;
        uh.u = make_uint2(pack2hi(p0, p1), pack2hi(p2, p3));
        v4s pH = uh.v;
        #pragma unroll
        for (int mt = 0; mt < 3; mt++) {
          v4f a = ot[mt][qt];
          a = MFMA16(vh[mt], pH, a);
          a = MFMA16(vl[mt], pH, a);
          ot[mt][qt] = a;
        }
      }
    }
  };

  // ---- pipelined main loop: stage(t+1) overlaps compute(t); 1 barrier/tile --
  stage(smem[0], 0);
  __syncthreads();
  for (int t = 0; t < NT_TILES; t++) {
    if (t + 1 < NT_TILES) stage(smem[(t + 1) & 1], t + 1);
    compute(smem[t & 1]);
    __syncthreads();
  }

  // ---- epilogue: per-wave complete rows — direct write, no cross-wave merge
  #pragma unroll
  for (int qt = 0; qt < 2; qt++) {
    lsum[qt] += __shfl_xor(lsum[qt], 16, 64);
    lsum[qt] += __shfl_xor(lsum[qt], 32, 64);
  }
  const int T = qy * 4 + w;            // 128 partial tiles of 32 rows
  float* Ob = (z == 0) ? Opart0 : (z == 1) ? Opart1 : (z == 2) ? Opart2 : Opart3;
  #pragma unroll
  for (int qt = 0; qt < 2; qt++) {
    int row = 16 * qt + li;
    float* Op = Ob + ((size_t)(head * 128 + T) * 32 + row) * 48;
    #pragma unroll
    for (int mt = 0; mt < 3; mt++) {
      *(float4*)(Op + 16 * mt + 4 * quad) =
          make_float4(ot[mt][qt][0], ot[mt][qt][1], ot[mt][qt][2], ot[mt][qt][3]);
    }
  }
  if (quad == 0) {
    #pragma unroll
    for (int qt = 0; qt < 2; qt++) {
      size_t midx = ((size_t)(z * 8 + head) * 128 + T) * 32 + 16 * qt + li;
      mpart[midx] = m2[qt];
      lpart[midx] = lsum[qt];
    }
  }
}

// ---- combine the 4 KV-quarter partials, normalize, split to hi/lo ----
// 128 q-tiles of 32 rows; 128 threads = 32 rows x 4 col-groups of 12.
__global__ __launch_bounds__(128) void attn_merge_kernel(
    const float* __restrict__ Opart0, const float* __restrict__ Opart1,
    const float* __restrict__ Opart2, const float* __restrict__ Opart3,
    const float* __restrict__ mpart, const float* __restrict__ lpart,
    ushort* __restrict__ aoH, ushort* __restrict__ aoL)
{
  const int h = blockIdx.x, qt = blockIdx.y;   // qt 0..127
  const int tid = threadIdx.x;
  const int row = tid >> 2;                    // 0..31
  const int cg = (tid & 3) * 12;
  const size_t tile = (size_t)h * 128 + qt;
  float m[4], l[4];
  #pragma unroll
  for (int z = 0; z < 4; z++) {
    size_t mi = ((size_t)(z * 8 + h) * 128 + qt) * 32 + row;
    m[z] = mpart[mi];
    l[z] = lpart[mi];
  }
  float M = fmaxf(fmaxf(m[0], m[1]), fmaxf(m[2], m[3]));
  float sz[4];
  float den = 0.f;
  #pragma unroll
  for (int z = 0; z < 4; z++) { sz[z] = EXP2F(m[z] - M); den += l[z] * sz[z]; }
  float inv = 1.f / den;
  #pragma unroll
  for (int z = 0; z < 4; z++) sz[z] *= inv;
  const size_t ro = (tile * 32 + row) * 48 + cg;
  const float* O[4] = {Opart0 + ro, Opart1 + ro, Opart2 + ro, Opart3 + ro};
  size_t outp = (size_t)(qt * 32 + row) * DIM + h * DH + cg;
  #pragma unroll
  for (int g = 0; g < 3; g++) {
    float v0 = 0.f, v1 = 0.f, v2 = 0.f, v3 = 0.f;
    #pragma unroll
    for (int z = 0; z < 4; z++) {
      float4 a = *(const float4*)(O[z] + g * 4);
      v0 += a.x * sz[z]; v1 += a.y * sz[z];
      v2 += a.z * sz[z]; v3 += a.w * sz[z];
    }
    ushort4 H, L;
    bsplit(v0, H.x, L.x); bsplit(v1, H.y, L.y);
    bsplit(v2, H.z, L.z); bsplit(v3, H.w, L.w);
    *(ushort4*)(aoH + outp + g * 4) = H;
    *(ushort4*)(aoL + outp + g * 4) = L;
  }
}

// ======================= final projection + sigmoid =======================

__global__ __launch_bounds__(256) void out_kernel(const float* __restrict__ h,
    const float* __restrict__ Wout, const float* __restrict__ bout,
    float* __restrict__ out)
{
  int gw = (blockIdx.x * 256 + threadIdx.x) >> 6;
  int lane = threadIdx.x & 63;
  if (gw >= N_NODES) return;
  float s = 0.f;
  #pragma unroll
  for (int c = 0; c < 6; c++)
    s += h[(size_t)gw * DIM + lane + c * 64] * Wout[lane + c * 64];
  #pragma unroll
  for (int off = 32; off >= 1; off >>= 1) s += __shfl_xor(s, off, 64);
  if (lane == 0) out[gw] = 1.f / (1.f + __expf(-(s + bout[0])));
}

// ======================= launch =======================

extern "C" void kernel_launch(void* const* d_in, const int* in_sizes, int n_in,
                              void* d_out, int out_size, void* d_ws, size_t ws_size,
                              hipStream_t stream)
{
  const float* node_emb = (const float*)d_in[0];
  const int*   edge_index = (const int*)d_in[1];
  const float* W_conv = (const float*)d_in[2];
  const float* b_conv = (const float*)d_in[3];
  const float* W_in   = (const float*)d_in[4];
  const float* b_in   = (const float*)d_in[5];
  const float* W_ao   = (const float*)d_in[6];
  const float* b_ao   = (const float*)d_in[7];
  const float* W_out  = (const float*)d_in[8];
  const float* b_out  = (const float*)d_in[9];
  float* out = (float*)d_out;

  const size_t ND = (size_t)N_NODES * DIM;       // 1572864
  const size_t WI = (size_t)QKVD * DIM;          // 442368
  const size_t WC = (size_t)DIM * DIM;           // 147456
  const size_t KTB = (size_t)8 * 128 * 4096;     // 4194304 ushorts (padded rows)
  const size_t VTB = (size_t)8 * 128 * 3072;     // 3145728 ushorts

  float* h      = (float*)d_ws;
  ushort* aggH  = (ushort*)(h + ND);
  ushort* aggL  = aggH + ND;
  ushort* qhi   = aggL + ND;
  ushort* qlo   = qhi + ND;
  ushort* ktb   = qlo + ND;      // [8][128] K tile images, 4096 B each
  ushort* vtb   = ktb + KTB;     // [8][128] V tile images, 3072 B each
  ushort* aoH   = vtb + VTB;
  ushort* aoL   = aoH + ND;
  ushort* wiH   = aoL + ND;
  ushort* wiL   = wiH + WI;
  ushort* waoH  = wiL + WI;
  ushort* waoL  = waoH + WC;
  ushort* wctH  = waoL + WC;
  ushort* wctL  = wctH + 3 * WC;
  ushort* wfH   = wctL + 3 * WC;
  ushort* wfL   = wfH + 3 * WI;
  float* wibc   = (float*)(wfL + 3 * WI);
  float* Opart1 = wibc + 3 * QKVD;               // 8*128*32*48 = ND floats
  float* Opart2 = Opart1 + ND;
  float* Opart3 = Opart2 + ND;
  float* mpart  = Opart3 + ND;                   // 4*8*128*32 = 131072
  float* lpart  = mpart + 131072;
  int* counts   = (int*)(lpart + 131072);
  int* offsets  = counts + N_NODES;
  int* cursor   = offsets + N_NODES + 1;
  int* ssrc     = cursor + N_NODES;

  // z=0 partials alias the agg hi/lo region (dead during attention: written by
  // aggregate, consumed by qkv_gemm, both strictly before attn in the stream).
  float* Opart0 = (float*)aggH;                  // ND floats

  const int* dst = edge_index;
  const int* src = edge_index + N_EDGES;

  // CSR build
  zero_counts_kernel<<<(N_NODES + 255) / 256, 256, 0, stream>>>(counts, cursor);
  count_kernel<<<N_EDGES / 256, 256, 0, stream>>>(dst, counts);
  scan_kernel<<<1, 1024, 0, stream>>>(counts, offsets);
  scatter_kernel<<<N_EDGES / 256, 256, 0, stream>>>(dst, src, offsets, cursor, ssrc);
  (void)hipMemcpyAsync(h, node_emb, ND * sizeof(float), hipMemcpyDeviceToDevice, stream);

  // weight prep
  transpose_split_kernel<<<dim3(12, 12, 3), dim3(32, 32), 0, stream>>>(W_conv, wctH, wctL);
  split_kernel<<<(int)(WI / 1024), 256, 0, stream>>>(W_in, wiH, wiL, (int)WI);
  split_kernel<<<(int)(WC / 1024), 256, 0, stream>>>(W_ao, waoH, waoL, (int)WC);
  wibc_kernel<<<864, 256, 0, stream>>>(W_in, b_conv, wibc);
  wprep_gemm<<<dim3(9, 3, 3), 256, 0, stream>>>(wiH, wiL, wctH, wctL, wfH, wfL);

  for (int l = 0; l < N_LAYERS; l++) {
    aggregate_kernel<<<N_NODES, 128, 0, stream>>>(h, ssrc, offsets, aggH, aggL);
    qkv_gemm<<<dim3(18, 64), 256, 0, stream>>>(
        wfH + (size_t)l * WI, wfL + (size_t)l * WI, aggH, aggL,
        wibc + (size_t)l * QKVD, b_in, counts,
        qhi, qlo, ktb, vtb);
    attn_kernel<<<dim3(32, 8, 4), 256, 0, stream>>>(
        qhi, qlo, ktb, vtb, Opart0, Opart1, Opart2, Opart3, mpart, lpart);
    attn_merge_kernel<<<dim3(8, 128), 128, 0, stream>>>(
        Opart0, Opart1, Opart2, Opart3, mpart, lpart, aoH, aoL);
    outproj_gemm<<<dim3(64, 6), 256, 0, stream>>>(
        aoH, aoL, waoH, waoL, b_ao, h);
  }
  out_kernel<<<1024, 256, 0, stream>>>(h, W_out, b_out, out);
}

// Round 16
// 680.305 us; speedup vs baseline: 1.0476x; 1.0476x over previous
//
#include <hip/hip_runtime.h>
#include <math.h>

#define N_NODES 4096
#define DIM 384
#define QKVD 1152
#define N_EDGES 131072
#define N_HEADS 8
#define DH 48
#define N_LAYERS 3

typedef short v4s __attribute__((ext_vector_type(4)));
typedef short v8s __attribute__((ext_vector_type(8)));
typedef float v4f __attribute__((ext_vector_type(4)));

#define MFMA32(A, B, C) __builtin_amdgcn_mfma_f32_16x16x32_bf16(A, B, C, 0, 0, 0)
#define MFMA16(A, B, C) __builtin_amdgcn_mfma_f32_16x16x16bf16_1k(A, B, C, 0, 0, 0)
#define EXP2F(x) __builtin_exp2f(x)

// ======================= CSR build (counting sort by dst) =======================

__global__ void zero_counts_kernel(int* counts, int* cursor) {
  int i = blockIdx.x * blockDim.x + threadIdx.x;
  if (i < N_NODES) { counts[i] = 0; cursor[i] = 0; }
}

__global__ void count_kernel(const int* __restrict__ dst, int* counts) {
  int e = blockIdx.x * blockDim.x + threadIdx.x;
  if (e < N_EDGES) atomicAdd(&counts[dst[e]], 1);
}

__global__ __launch_bounds__(1024) void scan_kernel(const int* __restrict__ counts,
                                                    int* __restrict__ offsets) {
  __shared__ int s[1024];
  int t = threadIdx.x;
  int base = t * 4;
  int c[4];
  int sum = 0;
  #pragma unroll
  for (int i = 0; i < 4; i++) { c[i] = counts[base + i]; sum += c[i]; }
  s[t] = sum;
  __syncthreads();
  for (int off = 1; off < 1024; off <<= 1) {
    int v = (t >= off) ? s[t - off] : 0;
    __syncthreads();
    s[t] += v;
    __syncthreads();
  }
  int excl = s[t] - sum;
  #pragma unroll
  for (int i = 0; i < 4; i++) { offsets[base + i] = excl; excl += c[i]; }
  if (t == 1023) offsets[N_NODES] = s[1023];
}

__global__ void scatter_kernel(const int* __restrict__ dst, const int* __restrict__ src,
                               const int* __restrict__ offsets, int* cursor,
                               int* __restrict__ ssrc) {
  int e = blockIdx.x * blockDim.x + threadIdx.x;
  if (e < N_EDGES) {
    int d = dst[e];
    int pos = atomicAdd(&cursor[d], 1);
    ssrc[offsets[d] + pos] = src[e];
  }
}

// ======================= bf16 split helpers =======================

__device__ __forceinline__ void bsplit(float v, ushort& hi, ushort& lo) {
  unsigned b = __float_as_uint(v);
  unsigned hb = b & 0xFFFF0000u;
  hi = (ushort)(b >> 16);
  float r = v - __uint_as_float(hb);
  lo = (ushort)(__float_as_uint(r) >> 16);
}

// pack hi16 of (a,b) into one dword (a in low half) — bf16 truncation
__device__ __forceinline__ unsigned pack2hi(float a, float b) {
  return __builtin_amdgcn_perm(__float_as_uint(b), __float_as_uint(a), 0x07060302u);
}

// ======================= neighbor aggregation (+ split epilogue) =================
// R22: vectorized float4 gather + ushort4 stores (measured neutral, kept).

__global__ __launch_bounds__(128) void aggregate_kernel(const float* __restrict__ h,
    const int* __restrict__ ssrc, const int* __restrict__ offsets,
    ushort* __restrict__ aggH, ushort* __restrict__ aggL) {
  int i = blockIdx.x;
  int t = threadIdx.x;
  if (t >= 96) return;                 // 96 x float4 = 384 channels
  int e0 = offsets[i], e1 = offsets[i + 1];
  float a0 = 0.f, a1 = 0.f, a2 = 0.f, a3 = 0.f;
  int e = e0;
  for (; e + 2 <= e1; e += 2) {        // 2x unroll: 2 independent b128 loads
    const float4 x = *((const float4*)(h + (size_t)ssrc[e] * DIM) + t);
    const float4 y = *((const float4*)(h + (size_t)ssrc[e + 1] * DIM) + t);
    a0 += x.x; a1 += x.y; a2 += x.z; a3 += x.w;
    a0 += y.x; a1 += y.y; a2 += y.z; a3 += y.w;
  }
  if (e < e1) {
    const float4 x = *((const float4*)(h + (size_t)ssrc[e] * DIM) + t);
    a0 += x.x; a1 += x.y; a2 += x.z; a3 += x.w;
  }
  ushort4 H, L;
  bsplit(a0, H.x, L.x); bsplit(a1, H.y, L.y);
  bsplit(a2, H.z, L.z); bsplit(a3, H.w, L.w);
  size_t base = (size_t)i * DIM + 4 * t;
  *(ushort4*)(aggH + base) = H;
  *(ushort4*)(aggL + base) = L;
}

// ======================= weight prep kernels =======================

__global__ void transpose_split_kernel(const float* __restrict__ Wc,
    ushort* __restrict__ wctH, ushort* __restrict__ wctL) {
  __shared__ float s[32][33];
  const int l = blockIdx.z;
  const float* W = Wc + (size_t)l * DIM * DIM;
  int tx = threadIdx.x, ty = threadIdx.y;
  s[ty][tx] = W[(size_t)(blockIdx.y * 32 + ty) * DIM + blockIdx.x * 32 + tx];
  __syncthreads();
  float v = s[tx][ty];
  ushort hi, lo;
  bsplit(v, hi, lo);
  size_t off = (size_t)l * DIM * DIM + (size_t)(blockIdx.x * 32 + ty) * DIM + blockIdx.y * 32 + tx;
  wctH[off] = hi;
  wctL[off] = lo;
}

__global__ void split_kernel(const float* __restrict__ src,
    ushort* __restrict__ hi, ushort* __restrict__ lo, int n) {
  int i = (blockIdx.x * 256 + threadIdx.x) * 4;
  if (i >= n) return;
  float4 v = *(const float4*)(src + i);
  ushort4 H, L;
  bsplit(v.x, H.x, L.x); bsplit(v.y, H.y, L.y);
  bsplit(v.z, H.z, L.z); bsplit(v.w, H.w, L.w);
  *(ushort4*)(hi + i) = H;
  *(ushort4*)(lo + i) = L;
}

// wibc[l][i] = dot(Wi[i,:], b_conv[l,:])
__global__ __launch_bounds__(256) void wibc_kernel(const float* __restrict__ Wi,
    const float* __restrict__ bconv, float* __restrict__ wibc) {
  int gw = (blockIdx.x * 256 + threadIdx.x) >> 6;
  int lane = threadIdx.x & 63;
  if (gw >= 3 * QKVD) return;
  int l = gw / QKVD, i = gw - l * QKVD;
  const float* w = Wi + (size_t)i * DIM;
  const float* b = bconv + (size_t)l * DIM;
  float s = 0.f;
  #pragma unroll
  for (int c = 0; c < 6; c++) s += w[lane + c * 64] * b[lane + c * 64];
  #pragma unroll
  for (int off = 32; off >= 1; off >>= 1) s += __shfl_xor(s, off, 64);
  if (lane == 0) wibc[gw] = s;
}

// ======================= split-bf16 MFMA GEMM cores ==============================

template<int K>
__device__ __forceinline__ void mfma_core(
    const ushort* __restrict__ Ah, const ushort* __restrict__ Al,
    const ushort* __restrict__ Bh, const ushort* __restrict__ Bl,
    int aRow0, int bRow0, int li, int quad, v4f acc[4][4])
{
  for (int k0 = 0; k0 < K; k0 += 32) {
    v8s Afh[4], Afl[4], Bfh[4], Bfl[4];
    #pragma unroll
    for (int t = 0; t < 4; t++) {
      size_t ao = (size_t)(aRow0 + t * 16 + li) * K + k0 + quad * 8;
      size_t bo = (size_t)(bRow0 + t * 16 + li) * K + k0 + quad * 8;
      Afh[t] = *(const v8s*)(Ah + ao);
      Afl[t] = *(const v8s*)(Al + ao);
      Bfh[t] = *(const v8s*)(Bh + bo);
      Bfl[t] = *(const v8s*)(Bl + bo);
    }
    #pragma unroll
    for (int mt = 0; mt < 4; mt++)
      #pragma unroll
      for (int nt = 0; nt < 4; nt++) {
        v4f a = acc[mt][nt];
        a = MFMA32(Afh[mt], Bfh[nt], a);
        a = MFMA32(Afl[mt], Bfh[nt], a);
        a = MFMA32(Afh[mt], Bfl[nt], a);
        acc[mt][nt] = a;
      }
  }
}

// 2x2-tile variant (32x32 per wave) — for small-output GEMMs needing more blocks
template<int K>
__device__ __forceinline__ void mfma_core2(
    const ushort* __restrict__ Ah, const ushort* __restrict__ Al,
    const ushort* __restrict__ Bh, const ushort* __restrict__ Bl,
    int aRow0, int bRow0, int li, int quad, v4f acc[2][2])
{
  for (int k0 = 0; k0 < K; k0 += 32) {
    v8s Afh[2], Afl[2], Bfh[2], Bfl[2];
    #pragma unroll
    for (int t = 0; t < 2; t++) {
      size_t ao = (size_t)(aRow0 + t * 16 + li) * K + k0 + quad * 8;
      size_t bo = (size_t)(bRow0 + t * 16 + li) * K + k0 + quad * 8;
      Afh[t] = *(const v8s*)(Ah + ao);
      Afl[t] = *(const v8s*)(Al + ao);
      Bfh[t] = *(const v8s*)(Bh + bo);
      Bfl[t] = *(const v8s*)(Bl + bo);
    }
    #pragma unroll
    for (int mt = 0; mt < 2; mt++)
      #pragma unroll
      for (int nt = 0; nt < 2; nt++) {
        v4f a = acc[mt][nt];
        a = MFMA32(Afh[mt], Bfh[nt], a);
        a = MFMA32(Afl[mt], Bfh[nt], a);
        a = MFMA32(Afh[mt], Bfl[nt], a);
        acc[mt][nt] = a;
      }
  }
}

// --- weight-prep GEMM: Wf[l] = Wi @ Wct[l] ---
__global__ __launch_bounds__(256) void wprep_gemm(
    const ushort* __restrict__ wiH, const ushort* __restrict__ wiL,
    const ushort* __restrict__ wctH, const ushort* __restrict__ wctL,
    ushort* __restrict__ wfH, ushort* __restrict__ wfL)
{
  const int l = blockIdx.z;
  const ushort* Bh = wctH + (size_t)l * DIM * DIM;
  const ushort* Bl = wctL + (size_t)l * DIM * DIM;
  ushort* oH = wfH + (size_t)l * QKVD * DIM;
  ushort* oL = wfL + (size_t)l * QKVD * DIM;
  const int tid = threadIdx.x;
  const int lane = tid & 63, li = lane & 15, quad = lane >> 4;
  const int w = tid >> 6, wm = w & 1, wn = w >> 1;
  const int aRow0 = blockIdx.x * 128 + wm * 64;
  const int bRow0 = blockIdx.y * 128 + wn * 64;
  v4f acc[4][4] = {};
  mfma_core<DIM>(wiH, wiL, Bh, Bl, aRow0, bRow0, li, quad, acc);
  #pragma unroll
  for (int mt = 0; mt < 4; mt++) {
    int i0 = aRow0 + mt * 16 + quad * 4;
    #pragma unroll
    for (int nt = 0; nt < 4; nt++) {
      int j = bRow0 + nt * 16 + li;
      #pragma unroll
      for (int r = 0; r < 4; r++) {
        ushort hi, lo;
        bsplit(acc[mt][nt][r], hi, lo);
        oH[(size_t)(i0 + r) * DIM + j] = hi;
        oL[(size_t)(i0 + r) * DIM + j] = lo;
      }
    }
  }
}

// --- fused qkv GEMM ---
// R24: reverted to the 128x128 / grid (9,32) configuration (the best-measured
// build). R23's 64x64 retile regressed +30us: a K=384 direct-global GEMM loads
// (rowsA+rowsB)*K*2 elements per block — 12 loads/output at 128^2 vs 24 at
// 64^2 — and qkv is L2-traffic-limited, not latency-starved (two ~90-VGPR
// blocks co-reside per CU, absorbing the 288-block grid's tail).
// K/V written as XOR-swizzled LDS-image tiles of 32 kcols (R16 layout):
//   K tile: 32 rows x 16 chunks of 16B; image chunk = logical ^ (row & 7).
//   V tile: 48 rows x 8 chunks of 16B; image chunk = g ^ (row & 7).
// R21 V-epilogue LDS coalescing kept (measured neutral, not harmful).
__global__ __launch_bounds__(256) void qkv_gemm(
    const ushort* __restrict__ wfH, const ushort* __restrict__ wfL,
    const ushort* __restrict__ aggH, const ushort* __restrict__ aggL,
    const float* __restrict__ wibc_l, const float* __restrict__ b_in,
    const int* __restrict__ deg,
    ushort* __restrict__ qhi, ushort* __restrict__ qlo,
    ushort* __restrict__ ktb, ushort* __restrict__ vtb)
{
  __shared__ ushort lhi[128][132];   // padded: 264B rows -> 8B-aligned ushort4
  __shared__ ushort llo[128][132];   // reads, bank-shifted fills
  const int tid = threadIdx.x;
  const int lane = tid & 63, li = lane & 15, quad = lane >> 4;
  const int w = tid >> 6, wm = w & 1, wn = w >> 1;
  const int bx = blockIdx.x;
  const int aRow0 = bx * 128 + wm * 64;           // channel base
  const int bRow0 = blockIdx.y * 128 + wn * 64;   // node base
  v4f acc[4][4] = {};
  mfma_core<DIM>(wfH, wfL, aggH, aggL, aRow0, bRow0, li, quad, acc);

  const float cq = 0.20823507f;  // log2(e)/sqrt(48)
  int node[4]; float degf[4];
  #pragma unroll
  for (int nt = 0; nt < 4; nt++) {
    node[nt] = bRow0 + nt * 16 + li;
    degf[nt] = (float)deg[node[nt]];
  }

  if (bx < 6) {
    // ---- Q (part 0) and K (part 1) blocks: original epilogue ----
    #pragma unroll
    for (int mt = 0; mt < 4; mt++) {
      const int c0 = aRow0 + mt * 16 + quad * 4;
      const int part = c0 / DIM;
      const int cm = c0 - part * DIM;
      const int hd = cm / DH;
      const int d0 = cm - hd * DH;
      float wb[4], bb[4];
      #pragma unroll
      for (int r = 0; r < 4; r++) { wb[r] = wibc_l[c0 + r]; bb[r] = b_in[c0 + r]; }
      #pragma unroll
      for (int nt = 0; nt < 4; nt++) {
        float v0 = acc[mt][nt][0] + degf[nt] * wb[0] + bb[0];
        float v1 = acc[mt][nt][1] + degf[nt] * wb[1] + bb[1];
        float v2 = acc[mt][nt][2] + degf[nt] * wb[2] + bb[2];
        float v3 = acc[mt][nt][3] + degf[nt] * wb[3] + bb[3];
        if (part == 0) {
          v0 *= cq; v1 *= cq; v2 *= cq; v3 *= cq;
          ushort4 H, L;
          bsplit(v0, H.x, L.x); bsplit(v1, H.y, L.y);
          bsplit(v2, H.z, L.z); bsplit(v3, H.w, L.w);
          size_t off = ((size_t)hd * N_NODES + node[nt]) * DH + d0;
          *(ushort4*)(qhi + off) = H;
          *(ushort4*)(qlo + off) = L;
        } else {
          ushort4 H, L;
          bsplit(v0, H.x, L.x); bsplit(v1, H.y, L.y);
          bsplit(v2, H.z, L.z); bsplit(v3, H.w, L.w);
          int kt = node[nt] >> 5, rc = node[nt] & 31;
          size_t base = (size_t)(hd * 128 + kt) * 4096 + (size_t)rc * 128;
          int ch = d0 >> 3, half = ((d0 >> 2) & 1) * 4;
          *(ushort4*)(ktb + base + ((ch ^ (rc & 7)) << 3) + half) = H;
          *(ushort4*)(ktb + base + (((ch + 6) ^ (rc & 7)) << 3) + half) = L;
        }
      }
    }
  } else {
    // ---- V blocks (part 2, channels 768..1151): LDS-staged coalesced path --
    #pragma unroll
    for (int mt = 0; mt < 4; mt++) {
      const int c0 = aRow0 + mt * 16 + quad * 4;      // global qkv channel
      const int lc0 = (wm * 64 + mt * 16 + quad * 4); // 0..127 within block
      float wb[4], bb[4];
      #pragma unroll
      for (int r = 0; r < 4; r++) { wb[r] = wibc_l[c0 + r]; bb[r] = b_in[c0 + r]; }
      #pragma unroll
      for (int nt = 0; nt < 4; nt++) {
        const int ln = wn * 64 + nt * 16 + li;        // 0..127 local node
        float vv[4];
        vv[0] = acc[mt][nt][0] + degf[nt] * wb[0] + bb[0];
        vv[1] = acc[mt][nt][1] + degf[nt] * wb[1] + bb[1];
        vv[2] = acc[mt][nt][2] + degf[nt] * wb[2] + bb[2];
        vv[3] = acc[mt][nt][3] + degf[nt] * wb[3] + bb[3];
        #pragma unroll
        for (int r = 0; r < 4; r++) {
          ushort hi, lo;
          bsplit(vv[r], hi, lo);
          lhi[lc0 + r][ln] = hi;
          llo[lc0 + r][ln] = lo;
        }
      }
    }
    __syncthreads();
    // cooperative writeout: 4096 slots = 128 lc x 4 ktl x 8 g; 16/thread.
    const int by = blockIdx.y;
    #pragma unroll
    for (int it = 0; it < 16; it++) {
      int item = it * 256 + tid;
      int lc = item >> 5;
      int rem = item & 31;
      int ktl = rem >> 3, g = rem & 7;
      int c = (bx - 6) * 128 + lc;         // v-channel 0..383
      int hd = c / DH, row = c - hd * DH;  // head, d-row 0..47
      int kt = by * 4 + ktl;               // tile 0..127
      ushort4 H = *(const ushort4*)&lhi[lc][ktl * 32 + g * 4];
      ushort4 L = *(const ushort4*)&llo[lc][ktl * 32 + g * 4];
      size_t base = (size_t)(hd * 128 + kt) * 3072 + (size_t)row * 64
                  + ((g ^ (row & 7)) << 3);
      *(ushort4*)(vtb + base) = H;
      *(ushort4*)(vtb + base + 4) = L;
    }
  }
}

// --- attn-out GEMM: h = relu(ao @ Wao^T + b_ao + h) ---
// R20: retiled 128x128 -> 64x64 (grid 96 -> 384 blocks); full-CU coverage.
__global__ __launch_bounds__(256) void outproj_gemm(
    const ushort* __restrict__ aoH, const ushort* __restrict__ aoL,
    const ushort* __restrict__ waoH, const ushort* __restrict__ waoL,
    const float* __restrict__ b_ao, float* __restrict__ h)
{
  const int tid = threadIdx.x;
  const int lane = tid & 63, li = lane & 15, quad = lane >> 4;
  const int w = tid >> 6, wm = w & 1, wn = w >> 1;
  const int aRow0 = blockIdx.x * 64 + wm * 32;   // node base
  const int bRow0 = blockIdx.y * 64 + wn * 32;   // channel base
  v4f acc[2][2] = {};
  mfma_core2<DIM>(aoH, aoL, waoH, waoL, aRow0, bRow0, li, quad, acc);
  #pragma unroll
  for (int mt = 0; mt < 2; mt++) {
    int m0 = aRow0 + mt * 16 + quad * 4;
    #pragma unroll
    for (int nt = 0; nt < 2; nt++) {
      int n = bRow0 + nt * 16 + li;
      float ba = b_ao[n];
      #pragma unroll
      for (int r = 0; r < 4; r++) {
        size_t off = (size_t)(m0 + r) * DIM + n;
        float v = acc[mt][nt][r] + ba + h[off];
        h[off] = fmaxf(v, 0.f);
      }
    }
  }
}

// ======================= MFMA flash attention (split-bf16, KV-split 4) ==========
// R16 configuration — the measured best (101-103 us/dispatch, reproduced
// across 6 runs). 32-kcol tiles, LDS double-buffer, 1 __syncthreads-pair per
// tile, 4 blocks/CU.

#define NT_TILES 32
#define K_TILE_B 8192
#define V_TILE_B 6144
#define TILE_B   (K_TILE_B + V_TILE_B)   // 14336; x2 buffers = 28672

__global__ __launch_bounds__(256, 4) void attn_kernel(
    const ushort* __restrict__ qhi, const ushort* __restrict__ qlo,
    const ushort* __restrict__ ktb, const ushort* __restrict__ vtb,
    float* __restrict__ Opart0, float* __restrict__ Opart1,
    float* __restrict__ Opart2, float* __restrict__ Opart3,
    float* __restrict__ mpart, float* __restrict__ lpart)
{
  const int head = blockIdx.y;
  const int qy = blockIdx.x;            // 0..31, 128 q-rows each
  const int z = blockIdx.z;             // 0..3 KV quarter (32 tiles of 32 kcols)
  const int tid = threadIdx.x;
  const int w = tid >> 6;
  const int lane = tid & 63;
  const int li = lane & 15, quad = lane >> 4;
  const int lx = li & 7;

  __shared__ __align__(16) char smem[2][TILE_B];

  // ---- resident Q fragments: wave w owns q-rows qy*128 + 32w + [0,32) ----
  const size_t headQ = (size_t)head * N_NODES * DH;
  const int qRow0 = qy * 128 + 32 * w;
  v8s q0h[2], q0l[2];
  v4s q1h[2], q1l[2];
  #pragma unroll
  for (int qt = 0; qt < 2; qt++) {
    const ushort* qr = qhi + headQ + (size_t)(qRow0 + 16 * qt + li) * DH;
    const ushort* ql = qlo + headQ + (size_t)(qRow0 + 16 * qt + li) * DH;
    q0h[qt] = *(const v8s*)(qr + quad * 8);
    q0l[qt] = *(const v8s*)(ql + quad * 8);
    q1h[qt] = *(const v4s*)(qr + 32 + quad * 4);
    q1l[qt] = *(const v4s*)(ql + 32 + quad * 4);
  }

  v4f ot[3][2];
  #pragma unroll
  for (int mt = 0; mt < 3; mt++)
    #pragma unroll
    for (int qt = 0; qt < 2; qt++)
      ot[mt][qt] = (v4f){0.f, 0.f, 0.f, 0.f};
  float m2[2] = {-3.0e38f, -3.0e38f};
  float lsum[2] = {0.f, 0.f};

  // ---- global tile-image bases for this (head, quarter) ----
  const char* gK = (const char*)ktb + (size_t)(head * 128 + z * 32) * K_TILE_B;
  const char* gV = (const char*)vtb + (size_t)(head * 128 + z * 32) * V_TILE_B;

  // ---- loop-invariant swizzled LDS read offsets ----
  const int koff_h  = ((quad ^ lx) << 4);
  const int koff_l  = (((6 + quad) ^ lx) << 4);
  const int koff_t0 = (((4 + (quad >> 1)) ^ lx) << 4) + ((quad & 1) << 3);
  const int koff_t1 = (((10 + (quad >> 1)) ^ lx) << 4) + ((quad & 1) << 3);

  // stage one tile (14 x 1KB chunks; wave w takes chunks w, w+4, w+8, w+12<14)
  auto stage = [&](char* sbase, int t) {
    const char* kt_ = gK + (size_t)t * K_TILE_B;
    const char* vt_ = gV + (size_t)t * V_TILE_B;
    #pragma unroll
    for (int j = 0; j < 4; j++) {
      const int ch = w + 4 * j;               // wave-uniform
      if (ch < 14) {
        const char* src = (ch < 8) ? (kt_ + (size_t)ch * 1024 + (size_t)lane * 16)
                                   : (vt_ + (size_t)(ch - 8) * 1024 + (size_t)lane * 16);
        __builtin_amdgcn_global_load_lds(
            (const __attribute__((address_space(1))) unsigned int*)src,
            (__attribute__((address_space(3))) unsigned int*)(sbase + ch * 1024),
            16, 0, 0);
      }
    }
  };

  auto compute = [&](const char* sbase) {
    const char* sK = sbase;
    const char* sV = sbase + K_TILE_B;
    #pragma unroll
    for (int ktl = 0; ktl < 2; ktl++) {
      // ---- K fragments (conflict-free swizzled reads) ----
      const char* kr = sK + ktl * 4096 + li * 256;
      v8s kh = *(const v8s*)(kr + koff_h);
      v8s kl = *(const v8s*)(kr + koff_l);
      v4s th = *(const v4s*)(kr + koff_t0);
      v4s tl = *(const v4s*)(kr + koff_t1);

      // ---- S^T = K·Q^T (split-3 exact, log2-domain) ----
      v4f s[2];
      #pragma unroll
      for (int qt = 0; qt < 2; qt++) {
        v4f a = (v4f){0.f, 0.f, 0.f, 0.f};
        a = MFMA32(kh, q0h[qt], a);
        a = MFMA32(kl, q0h[qt], a);
        a = MFMA32(kh, q0l[qt], a);
        a = MFMA16(th, q1h[qt], a);
        a = MFMA16(tl, q1h[qt], a);
        a = MFMA16(th, q1l[qt], a);
        s[qt] = a;
      }

      // ---- V fragments for this ktl (hi|lo interleaved in one b128) ----
      const int vcoff = (((4 * ktl + quad) ^ lx) << 4);
      v4s vh[3], vl[3];
      #pragma unroll
      for (int mt = 0; mt < 3; mt++) {
        v8s vv = *(const v8s*)(sV + mt * 2048 + li * 128 + vcoff);
        vh[mt] = __builtin_shufflevector(vv, vv, 0, 1, 2, 3);
        vl[mt] = __builtin_shufflevector(vv, vv, 4, 5, 6, 7);
      }

      // ---- guarded-base softmax + PV, fused per ktl (exact) ----
      #pragma unroll
      for (int qt = 0; qt < 2; qt++) {
        float mx = fmaxf(fmaxf(s[qt][0], s[qt][1]), fmaxf(s[qt][2], s[qt][3]));
        if (__any(mx > m2[qt] + 40.f)) {          // wave-uniform, rare
          float mr = fmaxf(mx, __shfl_xor(mx, 16, 64));
          mr = fmaxf(mr, __shfl_xor(mr, 32, 64)); // row-uniform new max
          float a = EXP2F(m2[qt] - fmaxf(m2[qt], mr));
          m2[qt] = fmaxf(m2[qt], mr);
          lsum[qt] *= a;
          #pragma unroll
          for (int mt = 0; mt < 3; mt++) ot[mt][qt] *= a;
        }
        float p0 = EXP2F(s[qt][0] - m2[qt]);      // bounded <= 2^40
        float p1 = EXP2F(s[qt][1] - m2[qt]);
        float p2 = EXP2F(s[qt][2] - m2[qt]);
        float p3 = EXP2F(s[qt][3] - m2[qt]);
        lsum[qt] += (p0 + p1) + (p2 + p3);
        union { uint2 u; v4s v; } uh;
        uh.u = make_uint2(pack2hi(p0, p1), pack2hi(p2, p3));
        v4s pH = uh.v;
        #pragma unroll
        for (int mt = 0; mt < 3; mt++) {
          v4f a = ot[mt][qt];
          a = MFMA16(vh[mt], pH, a);
          a = MFMA16(vl[mt], pH, a);
          ot[mt][qt] = a;
        }
      }
    }
  };

  // ---- pipelined main loop: stage(t+1) overlaps compute(t); 1 barrier/tile --
  stage(smem[0], 0);
  __syncthreads();
  for (int t = 0; t < NT_TILES; t++) {
    if (t + 1 < NT_TILES) stage(smem[(t + 1) & 1], t + 1);
    compute(smem[t & 1]);
    __syncthreads();
  }

  // ---- epilogue: per-wave complete rows — direct write, no cross-wave merge
  #pragma unroll
  for (int qt = 0; qt < 2; qt++) {
    lsum[qt] += __shfl_xor(lsum[qt], 16, 64);
    lsum[qt] += __shfl_xor(lsum[qt], 32, 64);
  }
  const int T = qy * 4 + w;            // 128 partial tiles of 32 rows
  float* Ob = (z == 0) ? Opart0 : (z == 1) ? Opart1 : (z == 2) ? Opart2 : Opart3;
  #pragma unroll
  for (int qt = 0; qt < 2; qt++) {
    int row = 16 * qt + li;
    float* Op = Ob + ((size_t)(head * 128 + T) * 32 + row) * 48;
    #pragma unroll
    for (int mt = 0; mt < 3; mt++) {
      *(float4*)(Op + 16 * mt + 4 * quad) =
          make_float4(ot[mt][qt][0], ot[mt][qt][1], ot[mt][qt][2], ot[mt][qt][3]);
    }
  }
  if (quad == 0) {
    #pragma unroll
    for (int qt = 0; qt < 2; qt++) {
      size_t midx = ((size_t)(z * 8 + head) * 128 + T) * 32 + 16 * qt + li;
      mpart[midx] = m2[qt];
      lpart[midx] = lsum[qt];
    }
  }
}

// ---- combine the 4 KV-quarter partials, normalize, split to hi/lo ----
// 128 q-tiles of 32 rows; 128 threads = 32 rows x 4 col-groups of 12.
__global__ __launch_bounds__(128) void attn_merge_kernel(
    const float* __restrict__ Opart0, const float* __restrict__ Opart1,
    const float* __restrict__ Opart2, const float* __restrict__ Opart3,
    const float* __restrict__ mpart, const float* __restrict__ lpart,
    ushort* __restrict__ aoH, ushort* __restrict__ aoL)
{
  const int h = blockIdx.x, qt = blockIdx.y;   // qt 0..127
  const int tid = threadIdx.x;
  const int row = tid >> 2;                    // 0..31
  const int cg = (tid & 3) * 12;
  const size_t tile = (size_t)h * 128 + qt;
  float m[4], l[4];
  #pragma unroll
  for (int z = 0; z < 4; z++) {
    size_t mi = ((size_t)(z * 8 + h) * 128 + qt) * 32 + row;
    m[z] = mpart[mi];
    l[z] = lpart[mi];
  }
  float M = fmaxf(fmaxf(m[0], m[1]), fmaxf(m[2], m[3]));
  float sz[4];
  float den = 0.f;
  #pragma unroll
  for (int z = 0; z < 4; z++) { sz[z] = EXP2F(m[z] - M); den += l[z] * sz[z]; }
  float inv = 1.f / den;
  #pragma unroll
  for (int z = 0; z < 4; z++) sz[z] *= inv;
  const size_t ro = (tile * 32 + row) * 48 + cg;
  const float* O[4] = {Opart0 + ro, Opart1 + ro, Opart2 + ro, Opart3 + ro};
  size_t outp = (size_t)(qt * 32 + row) * DIM + h * DH + cg;
  #pragma unroll
  for (int g = 0; g < 3; g++) {
    float v0 = 0.f, v1 = 0.f, v2 = 0.f, v3 = 0.f;
    #pragma unroll
    for (int z = 0; z < 4; z++) {
      float4 a = *(const float4*)(O[z] + g * 4);
      v0 += a.x * sz[z]; v1 += a.y * sz[z];
      v2 += a.z * sz[z]; v3 += a.w * sz[z];
    }
    ushort4 H, L;
    bsplit(v0, H.x, L.x); bsplit(v1, H.y, L.y);
    bsplit(v2, H.z, L.z); bsplit(v3, H.w, L.w);
    *(ushort4*)(aoH + outp + g * 4) = H;
    *(ushort4*)(aoL + outp + g * 4) = L;
  }
}

// ======================= final projection + sigmoid =======================

__global__ __launch_bounds__(256) void out_kernel(const float* __restrict__ h,
    const float* __restrict__ Wout, const float* __restrict__ bout,
    float* __restrict__ out)
{
  int gw = (blockIdx.x * 256 + threadIdx.x) >> 6;
  int lane = threadIdx.x & 63;
  if (gw >= N_NODES) return;
  float s = 0.f;
  #pragma unroll
  for (int c = 0; c < 6; c++)
    s += h[(size_t)gw * DIM + lane + c * 64] * Wout[lane + c * 64];
  #pragma unroll
  for (int off = 32; off >= 1; off >>= 1) s += __shfl_xor(s, off, 64);
  if (lane == 0) out[gw] = 1.f / (1.f + __expf(-(s + bout[0])));
}

// ======================= launch =======================

extern "C" void kernel_launch(void* const* d_in, const int* in_sizes, int n_in,
                              void* d_out, int out_size, void* d_ws, size_t ws_size,
                              hipStream_t stream)
{
  const float* node_emb = (const float*)d_in[0];
  const int*   edge_index = (const int*)d_in[1];
  const float* W_conv = (const float*)d_in[2];
  const float* b_conv = (const float*)d_in[3];
  const float* W_in   = (const float*)d_in[4];
  const float* b_in   = (const float*)d_in[5];
  const float* W_ao   = (const float*)d_in[6];
  const float* b_ao   = (const float*)d_in[7];
  const float* W_out  = (const float*)d_in[8];
  const float* b_out  = (const float*)d_in[9];
  float* out = (float*)d_out;

  const size_t ND = (size_t)N_NODES * DIM;       // 1572864
  const size_t WI = (size_t)QKVD * DIM;          // 442368
  const size_t WC = (size_t)DIM * DIM;           // 147456
  const size_t KTB = (size_t)8 * 128 * 4096;     // 4194304 ushorts (padded rows)
  const size_t VTB = (size_t)8 * 128 * 3072;     // 3145728 ushorts

  float* h      = (float*)d_ws;
  ushort* aggH  = (ushort*)(h + ND);
  ushort* aggL  = aggH + ND;
  ushort* qhi   = aggL + ND;
  ushort* qlo   = qhi + ND;
  ushort* ktb   = qlo + ND;      // [8][128] K tile images, 4096 B each
  ushort* vtb   = ktb + KTB;     // [8][128] V tile images, 3072 B each
  ushort* aoH   = vtb + VTB;
  ushort* aoL   = aoH + ND;
  ushort* wiH   = aoL + ND;
  ushort* wiL   = wiH + WI;
  ushort* waoH  = wiL + WI;
  ushort* waoL  = waoH + WC;
  ushort* wctH  = waoL + WC;
  ushort* wctL  = wctH + 3 * WC;
  ushort* wfH   = wctL + 3 * WC;
  ushort* wfL   = wfH + 3 * WI;
  float* wibc   = (float*)(wfL + 3 * WI);
  float* Opart1 = wibc + 3 * QKVD;               // 8*128*32*48 = ND floats
  float* Opart2 = Opart1 + ND;
  float* Opart3 = Opart2 + ND;
  float* mpart  = Opart3 + ND;                   // 4*8*128*32 = 131072
  float* lpart  = mpart + 131072;
  int* counts   = (int*)(lpart + 131072);
  int* offsets  = counts + N_NODES;
  int* cursor   = offsets + N_NODES + 1;
  int* ssrc     = cursor + N_NODES;

  // z=0 partials alias the agg hi/lo region (dead during attention: written by
  // aggregate, consumed by qkv_gemm, both strictly before attn in the stream).
  float* Opart0 = (float*)aggH;                  // ND floats

  const int* dst = edge_index;
  const int* src = edge_index + N_EDGES;

  // CSR build
  zero_counts_kernel<<<(N_NODES + 255) / 256, 256, 0, stream>>>(counts, cursor);
  count_kernel<<<N_EDGES / 256, 256, 0, stream>>>(dst, counts);
  scan_kernel<<<1, 1024, 0, stream>>>(counts, offsets);
  scatter_kernel<<<N_EDGES / 256, 256, 0, stream>>>(dst, src, offsets, cursor, ssrc);
  (void)hipMemcpyAsync(h, node_emb, ND * sizeof(float), hipMemcpyDeviceToDevice, stream);

  // weight prep
  transpose_split_kernel<<<dim3(12, 12, 3), dim3(32, 32), 0, stream>>>(W_conv, wctH, wctL);
  split_kernel<<<(int)(WI / 1024), 256, 0, stream>>>(W_in, wiH, wiL, (int)WI);
  split_kernel<<<(int)(WC / 1024), 256, 0, stream>>>(W_ao, waoH, waoL, (int)WC);
  wibc_kernel<<<864, 256, 0, stream>>>(W_in, b_conv, wibc);
  wprep_gemm<<<dim3(9, 3, 3), 256, 0, stream>>>(wiH, wiL, wctH, wctL, wfH, wfL);

  for (int l = 0; l < N_LAYERS; l++) {
    aggregate_kernel<<<N_NODES, 128, 0, stream>>>(h, ssrc, offsets, aggH, aggL);
    qkv_gemm<<<dim3(9, 32), 256, 0, stream>>>(
        wfH + (size_t)l * WI, wfL + (size_t)l * WI, aggH, aggL,
        wibc + (size_t)l * QKVD, b_in, counts,
        qhi, qlo, ktb, vtb);
    attn_kernel<<<dim3(32, 8, 4), 256, 0, stream>>>(
        qhi, qlo, ktb, vtb, Opart0, Opart1, Opart2, Opart3, mpart, lpart);
    attn_merge_kernel<<<dim3(8, 128), 128, 0, stream>>>(
        Opart0, Opart1, Opart2, Opart3, mpart, lpart, aoH, aoL);
    outproj_gemm<<<dim3(64, 6), 256, 0, stream>>>(
        aoH, aoL, waoH, waoL, b_ao, h);
  }
  out_kernel<<<1024, 256, 0, stream>>>(h, W_out, b_out, out);
}